// Round 1
// baseline (1039.106 us; speedup 1.0000x reference)
//
#include <hip/hip_runtime.h>
#include <math.h>

#define Bq 4
#define Nn 384
#define TT 4
#define RR 4
#define HH 8
#define DKk 16
#define HTD 512   // H*T*DK  per-node q layout [h][t][d]
#define KRN 2048  // per-node kr/vr floats, layout [r][h][s][d]

__device__ __forceinline__ void ld16(const float* __restrict__ p, float* o) {
  const float4* p4 = reinterpret_cast<const float4*>(p);
  float4 a = p4[0], b = p4[1], c = p4[2], d = p4[3];
  o[0]=a.x; o[1]=a.y; o[2]=a.z; o[3]=a.w;
  o[4]=b.x; o[5]=b.y; o[6]=b.z; o[7]=b.w;
  o[8]=c.x; o[9]=c.y; o[10]=c.z; o[11]=c.w;
  o[12]=d.x; o[13]=d.y; o[14]=d.z; o[15]=d.w;
}

// K1: per 8-node group: q/k/v projections, then kr = k·rel_att[r], vr = v·rel_msg[r]
__global__ __launch_bounds__(128) void k1_proj(
    const float* __restrict__ nf,
    const float* __restrict__ kw, const float* __restrict__ kb,
    const float* __restrict__ qw, const float* __restrict__ qb,
    const float* __restrict__ vw, const float* __restrict__ vb,
    const float* __restrict__ rel_att, const float* __restrict__ rel_msg,
    float* __restrict__ q_ws, float* __restrict__ kr_ws, float* __restrict__ vr_ws)
{
  __shared__ float nf_s[8][128];
  __shared__ float k_s[8][TT][HH][DKk];
  __shared__ float v_s[8][TT][HH][DKk];
  int bid = blockIdx.x;             // 0..191
  int b = bid / 48;
  int n0 = (bid % 48) * 8;
  int tid = threadIdx.x;            // 128 threads = output column c
  for (int x = tid; x < 8*128; x += 128)
    nf_s[x >> 7][x & 127] = nf[(size_t)(b*Nn + n0)*128 + x];
  __syncthreads();
  int c = tid;
  int h = c >> 4, d = c & 15;
  for (int t = 0; t < TT; ++t) {
    float aq[8], ak[8], av[8];
    float bq = qb[t*128 + c], bk = kb[t*128 + c], bv = vb[t*128 + c];
#pragma unroll
    for (int ni = 0; ni < 8; ++ni) { aq[ni]=bq; ak[ni]=bk; av[ni]=bv; }
    for (int i = 0; i < 128; ++i) {
      float wq = qw[(size_t)(t*128 + i)*128 + c];
      float wk = kw[(size_t)(t*128 + i)*128 + c];
      float wv = vw[(size_t)(t*128 + i)*128 + c];
#pragma unroll
      for (int ni = 0; ni < 8; ++ni) {
        float x = nf_s[ni][i];
        aq[ni] += x*wq; ak[ni] += x*wk; av[ni] += x*wv;
      }
    }
#pragma unroll
    for (int ni = 0; ni < 8; ++ni) {
      q_ws[(size_t)(b*Nn + n0 + ni)*HTD + h*64 + t*16 + d] = aq[ni];
      k_s[ni][t][h][d] = ak[ni];
      v_s[ni][t][h][d] = av[ni];
    }
  }
  __syncthreads();
  for (int r = 0; r < RR; ++r) {
    float ra[16], rm[16];
#pragma unroll
    for (int e = 0; e < 16; ++e) {
      ra[e] = rel_att[((size_t)(r*8 + h)*16 + e)*16 + d];
      rm[e] = rel_msg[((size_t)(r*8 + h)*16 + e)*16 + d];
    }
    for (int ni = 0; ni < 8; ++ni) {
#pragma unroll
      for (int s = 0; s < TT; ++s) {
        float accK = 0.f, accV = 0.f;
#pragma unroll
        for (int e = 0; e < 16; ++e) {
          accK += k_s[ni][s][h][e] * ra[e];
          accV += v_s[ni][s][h][e] * rm[e];
        }
        size_t base = (size_t)(b*Nn + n0 + ni)*KRN + r*512 + h*64 + s*16 + d;
        kr_ws[base] = accK;
        vr_ws[base] = accV;
      }
    }
  }
}

// K2: res_att[b,h,i,j]
__global__ __launch_bounds__(256) void k2_att(
    const float* __restrict__ nt, const float* __restrict__ adj,
    const float* __restrict__ ets, const float* __restrict__ rel_pri,
    const float* __restrict__ q_ws, const float* __restrict__ kr_ws,
    float* __restrict__ res_att)
{
  __shared__ float q_s[4][HTD];
  __shared__ float nti_s[4][TT];
  int jc = blockIdx.x, it = blockIdx.y, b = blockIdx.z;
  int i0 = it*4;
  int tid = threadIdx.x;
  int j_l = tid & 31, h = tid >> 5;
  for (int x = tid; x < 4*HTD; x += 256)
    q_s[x >> 9][x & 511] = q_ws[(size_t)(b*Nn + i0)*HTD + x];
  if (tid < 16) nti_s[tid >> 2][tid & 3] = nt[(size_t)(b*Nn + i0 + (tid >> 2))*TT + (tid & 3)];
  __syncthreads();
  int j = jc*32 + j_l;
  float ntj[TT];
#pragma unroll
  for (int t = 0; t < TT; ++t) ntj[t] = nt[(size_t)(b*Nn + j)*TT + t];
  float qn[4][16];
#pragma unroll
  for (int i = 0; i < 4; ++i)
#pragma unroll
    for (int d = 0; d < 16; ++d) {
      float a = q_s[i][h*64 + d]     * ntj[0];
      a      += q_s[i][h*64 + 16 + d]* ntj[1];
      a      += q_s[i][h*64 + 32 + d]* ntj[2];
      a      += q_s[i][h*64 + 48 + d]* ntj[3];
      qn[i][d] = a;
    }
  float wvadj[4], mar[4][4];
#pragma unroll
  for (int i = 0; i < 4; ++i) {
    wvadj[i] = adj[(size_t)(b*Nn + i0 + i)*Nn + j];
    float4 e4 = *reinterpret_cast<const float4*>(&ets[((size_t)(b*Nn + i0 + i)*Nn + j)*RR]);
    mar[i][0]=e4.x*wvadj[i]; mar[i][1]=e4.y*wvadj[i]; mar[i][2]=e4.z*wvadj[i]; mar[i][3]=e4.w*wvadj[i];
  }
  float acc[4] = {0.f,0.f,0.f,0.f};
  const float* krb = kr_ws + (size_t)(b*Nn + j)*KRN + h*64;
#pragma unroll
  for (int r = 0; r < RR; ++r) {
    float cr = rel_pri[r*HH + h] * 0.25f;   // 1/sqrt(16)
#pragma unroll
    for (int s = 0; s < TT; ++s) {
      float kk[16];
      ld16(krb + r*512 + s*16, kk);
#pragma unroll
      for (int i = 0; i < 4; ++i) {
        float dot = 0.f;
#pragma unroll
        for (int d = 0; d < 16; ++d) dot += qn[i][d]*kk[d];
        acc[i] += mar[i][r] * cr * nti_s[i][s] * dot;
      }
    }
  }
#pragma unroll
  for (int i = 0; i < 4; ++i)
    res_att[((size_t)(b*HH + h)*Nn + (i0 + i))*Nn + j] = acc[i];
}

// K3: att_inv[b,h,j] = guarded 1/sum_i res_att
__global__ __launch_bounds__(128) void k3_attsum(
    const float* __restrict__ res_att, float* __restrict__ att_inv)
{
  int jc = blockIdx.x, h = blockIdx.y, b = blockIdx.z;
  int j = jc*128 + threadIdx.x;
  const float* p = res_att + (size_t)(b*HH + h)*Nn*Nn + j;
  float s = 0.f;
  for (int i = 0; i < Nn; ++i) s += p[(size_t)i*Nn];
  att_inv[(size_t)(b*HH + h)*Nn + j] = (s > 1e-6f) ? 1.f/s : 0.f;
}

// K4: agg partial over half the j range
__global__ __launch_bounds__(256) void k4_agg(
    const float* __restrict__ nt, const float* __restrict__ adj,
    const float* __restrict__ ets, const float* __restrict__ rel_pri,
    const float* __restrict__ q_ws, const float* __restrict__ kr_ws,
    const float* __restrict__ vr_ws, const float* __restrict__ res_att,
    const float* __restrict__ att_inv, float* __restrict__ agg_part)
{
  __shared__ float q_s[4][HTD];
  __shared__ float nti_s[4][TT];
  int js = blockIdx.x, it = blockIdx.y, b = blockIdx.z;
  int i0 = it*4;
  int tid = threadIdx.x;
  int j_l = tid & 31, h = tid >> 5;
  for (int x = tid; x < 4*HTD; x += 256)
    q_s[x >> 9][x & 511] = q_ws[(size_t)(b*Nn + i0)*HTD + x];
  if (tid < 16) nti_s[tid >> 2][tid & 3] = nt[(size_t)(b*Nn + i0 + (tid >> 2))*TT + (tid & 3)];
  __syncthreads();
  float aggp[4][16];
#pragma unroll
  for (int i = 0; i < 4; ++i)
#pragma unroll
    for (int d = 0; d < 16; ++d) aggp[i][d] = 0.f;

  for (int jj = 0; jj < 6; ++jj) {
    int j = js*192 + jj*32 + j_l;
    float ntj[TT];
#pragma unroll
    for (int t = 0; t < TT; ++t) ntj[t] = nt[(size_t)(b*Nn + j)*TT + t];
    float qn[4][16];
#pragma unroll
    for (int i = 0; i < 4; ++i)
#pragma unroll
      for (int d = 0; d < 16; ++d) {
        float a = q_s[i][h*64 + d]     * ntj[0];
        a      += q_s[i][h*64 + 16 + d]* ntj[1];
        a      += q_s[i][h*64 + 32 + d]* ntj[2];
        a      += q_s[i][h*64 + 48 + d]* ntj[3];
        qn[i][d] = a;
      }
    float inv = att_inv[(size_t)(b*HH + h)*Nn + j];
    float wv[4], mar[4][4];
#pragma unroll
    for (int i = 0; i < 4; ++i) {
      wv[i] = res_att[((size_t)(b*HH + h)*Nn + (i0 + i))*Nn + j] * inv;
      float av = adj[(size_t)(b*Nn + i0 + i)*Nn + j];
      float4 e4 = *reinterpret_cast<const float4*>(&ets[((size_t)(b*Nn + i0 + i)*Nn + j)*RR]);
      mar[i][0]=e4.x*av; mar[i][1]=e4.y*av; mar[i][2]=e4.z*av; mar[i][3]=e4.w*av;
    }
    const float* krb = kr_ws + (size_t)(b*Nn + j)*KRN + h*64;
    const float* vrb = vr_ws + (size_t)(b*Nn + j)*KRN + h*64;
#pragma unroll
    for (int r = 0; r < RR; ++r) {
      float cr = rel_pri[r*HH + h] * 0.25f;
#pragma unroll
      for (int s = 0; s < TT; ++s) {
        float kk[16], vv[16];
        ld16(krb + r*512 + s*16, kk);
        ld16(vrb + r*512 + s*16, vv);
#pragma unroll
        for (int i = 0; i < 4; ++i) {
          float dot = 0.f;
#pragma unroll
          for (int d = 0; d < 16; ++d) dot += qn[i][d]*kk[d];
          float coef = wv[i] * mar[i][r] * cr * nti_s[i][s] * dot;
#pragma unroll
          for (int d = 0; d < 16; ++d) aggp[i][d] += coef * vv[d];
        }
      }
    }
  }
#pragma unroll
  for (int i = 0; i < 4; ++i)
#pragma unroll
    for (int d = 0; d < 16; ++d) {
      float v = aggp[i][d];
      v += __shfl_xor(v, 16);
      v += __shfl_xor(v, 8);
      v += __shfl_xor(v, 4);
      v += __shfl_xor(v, 2);
      v += __shfl_xor(v, 1);
      aggp[i][d] = v;
    }
  if (j_l == 0) {
#pragma unroll
    for (int i = 0; i < 4; ++i)
#pragma unroll
      for (int d = 0; d < 16; ++d)
        agg_part[(size_t)js*(Bq*Nn*128) + (size_t)(b*Nn + i0 + i)*128 + h*16 + d] = aggp[i][d];
  }
}

// K5: trans = agg·aw + ab, GELU, skip-gate, LayerNorm, type-mix
__global__ __launch_bounds__(128) void k5_out(
    const float* __restrict__ agg_part, const float* __restrict__ nf,
    const float* __restrict__ nt, const float* __restrict__ aw,
    const float* __restrict__ ab, const float* __restrict__ norm_w,
    const float* __restrict__ norm_b, const float* __restrict__ skip,
    float* __restrict__ out)
{
  __shared__ float agg_s[128];
  __shared__ float red[4];
  int n = blockIdx.x, b = blockIdx.y;
  int o = threadIdx.x;
  size_t node = (size_t)b*Nn + n;
  agg_s[o] = agg_part[node*128 + o] + agg_part[(size_t)(Bq*Nn*128) + node*128 + o];
  __syncthreads();
  float nfo = nf[node*128 + o];
  float outacc = 0.f;
  for (int t = 0; t < TT; ++t) {
    float a = ab[t*128 + o];
    for (int dd = 0; dd < 128; ++dd) a += agg_s[dd] * aw[(size_t)(t*128 + dd)*128 + o];
    float g = 0.5f * a * (1.f + erff(a * 0.70710678118654752f));
    float alpha = 1.f / (1.f + expf(-skip[t]));
    float res = g*alpha + nfo*(1.f - alpha);
    float s1 = res, s2 = res*res;
#pragma unroll
    for (int m = 32; m >= 1; m >>= 1) { s1 += __shfl_xor(s1, m); s2 += __shfl_xor(s2, m); }
    int w = o >> 6;
    if ((o & 63) == 0) { red[w*2] = s1; red[w*2 + 1] = s2; }
    __syncthreads();
    float tot1 = red[0] + red[2], tot2 = red[1] + red[3];
    __syncthreads();
    float mean = tot1 * (1.f/128.f);
    float var  = tot2 * (1.f/128.f) - mean*mean;
    float nrm = (res - mean) * rsqrtf(var + 1e-5f) * norm_w[t*128 + o] + norm_b[t*128 + o];
    outacc += nrm * nt[node*TT + t];
  }
  out[node*128 + o] = outacc;
}

extern "C" void kernel_launch(void* const* d_in, const int* in_sizes, int n_in,
                              void* d_out, int out_size, void* d_ws, size_t ws_size,
                              hipStream_t stream) {
  const float* nf      = (const float*)d_in[0];
  const float* nts     = (const float*)d_in[1];
  const float* adj     = (const float*)d_in[2];
  const float* ets     = (const float*)d_in[3];
  const float* kw      = (const float*)d_in[4];
  const float* kb      = (const float*)d_in[5];
  const float* qw      = (const float*)d_in[6];
  const float* qb      = (const float*)d_in[7];
  const float* vw      = (const float*)d_in[8];
  const float* vb      = (const float*)d_in[9];
  const float* aw      = (const float*)d_in[10];
  const float* ab      = (const float*)d_in[11];
  const float* normw   = (const float*)d_in[12];
  const float* normb   = (const float*)d_in[13];
  const float* rel_pri = (const float*)d_in[14];
  const float* rel_att = (const float*)d_in[15];
  const float* rel_msg = (const float*)d_in[16];
  const float* skip    = (const float*)d_in[17];
  (void)in_sizes; (void)n_in; (void)out_size; (void)ws_size;

  float* ws = (float*)d_ws;
  float* q_ws    = ws;                       // 786432
  float* kr_ws   = q_ws + (size_t)Bq*Nn*HTD; // 3145728
  float* vr_ws   = kr_ws + (size_t)Bq*Nn*KRN;
  float* res_att = vr_ws + (size_t)Bq*Nn*KRN;        // 4718592
  float* att_inv = res_att + (size_t)Bq*HH*Nn*Nn;    // 12288
  float* agg_p   = att_inv + (size_t)Bq*HH*Nn;       // 2*196608

  hipLaunchKernelGGL(k1_proj, dim3(192), dim3(128), 0, stream,
                     nf, kw, kb, qw, qb, vw, vb, rel_att, rel_msg, q_ws, kr_ws, vr_ws);
  hipLaunchKernelGGL(k2_att, dim3(12, 96, 4), dim3(256), 0, stream,
                     nts, adj, ets, rel_pri, q_ws, kr_ws, res_att);
  hipLaunchKernelGGL(k3_attsum, dim3(3, 8, 4), dim3(128), 0, stream, res_att, att_inv);
  hipLaunchKernelGGL(k4_agg, dim3(2, 96, 4), dim3(256), 0, stream,
                     nts, adj, ets, rel_pri, q_ws, kr_ws, vr_ws, res_att, att_inv, agg_p);
  hipLaunchKernelGGL(k5_out, dim3(384, 4), dim3(128), 0, stream,
                     agg_p, nf, nts, aw, ab, normw, normb, skip, (float*)d_out);
}

// Round 2
// 450.819 us; speedup vs baseline: 2.3049x; 2.3049x over previous
//
#include <hip/hip_runtime.h>
#include <math.h>

#define Bq 4
#define Nn 384
#define TT 4
#define RR 4
#define HH 8
#define DKk 16

// layouts:
//  q_ws : [h][node][t][d]            node = b*384+n, 64 f per (h,node)
//  kr_ws: [h][node][r][s][d]         256 f per (h,node)
//  vr_ws: same as kr_ws
//  res_att: [b][h][i][j]
//  att_inv: [b][h][j]
//  agg  : [node][h*16+d]

// K1: per 8-node group: q/k/v projections, then kr = k.rel_att[r], vr = v.rel_msg[r]
__global__ __launch_bounds__(128) void k1_proj(
    const float* __restrict__ nf,
    const float* __restrict__ kw, const float* __restrict__ kb,
    const float* __restrict__ qw, const float* __restrict__ qb,
    const float* __restrict__ vw, const float* __restrict__ vb,
    const float* __restrict__ rel_att, const float* __restrict__ rel_msg,
    float* __restrict__ q_ws, float* __restrict__ kr_ws, float* __restrict__ vr_ws)
{
  __shared__ float nf_s[8][128];
  __shared__ float k_s[8][TT][HH][DKk];
  __shared__ float v_s[8][TT][HH][DKk];
  int bid = blockIdx.x;             // 0..191
  int b = bid / 48;
  int n0 = (bid % 48) * 8;
  int tid = threadIdx.x;            // 128 threads = output column c
  for (int x = tid; x < 8*128; x += 128)
    nf_s[x >> 7][x & 127] = nf[(size_t)(b*Nn + n0)*128 + x];
  __syncthreads();
  int c = tid;
  int h = c >> 4, d = c & 15;
  for (int t = 0; t < TT; ++t) {
    float aq[8], ak[8], av[8];
    float bqv = qb[t*128 + c], bkv = kb[t*128 + c], bvv = vb[t*128 + c];
#pragma unroll
    for (int ni = 0; ni < 8; ++ni) { aq[ni]=bqv; ak[ni]=bkv; av[ni]=bvv; }
    for (int i = 0; i < 128; ++i) {
      float wq = qw[(size_t)(t*128 + i)*128 + c];
      float wk = kw[(size_t)(t*128 + i)*128 + c];
      float wv = vw[(size_t)(t*128 + i)*128 + c];
#pragma unroll
      for (int ni = 0; ni < 8; ++ni) {
        float x = nf_s[ni][i];
        aq[ni] += x*wq; ak[ni] += x*wk; av[ni] += x*wv;
      }
    }
#pragma unroll
    for (int ni = 0; ni < 8; ++ni) {
      q_ws[((size_t)(h*Bq*Nn) + b*Nn + n0 + ni)*64 + t*16 + d] = aq[ni];
      k_s[ni][t][h][d] = ak[ni];
      v_s[ni][t][h][d] = av[ni];
    }
  }
  __syncthreads();
  for (int r = 0; r < RR; ++r) {
    float ra[16], rm[16];
#pragma unroll
    for (int e = 0; e < 16; ++e) {
      ra[e] = rel_att[((size_t)(r*8 + h)*16 + e)*16 + d];
      rm[e] = rel_msg[((size_t)(r*8 + h)*16 + e)*16 + d];
    }
    for (int ni = 0; ni < 8; ++ni) {
#pragma unroll
      for (int s = 0; s < TT; ++s) {
        float accK = 0.f, accV = 0.f;
#pragma unroll
        for (int e = 0; e < 16; ++e) {
          accK += k_s[ni][s][h][e] * ra[e];
          accV += v_s[ni][s][h][e] * rm[e];
        }
        size_t base = ((size_t)(h*Bq*Nn) + b*Nn + n0 + ni)*256 + r*64 + s*16 + d;
        kr_ws[base] = accK;
        vr_ws[base] = accV;
      }
    }
  }
}

// ---- K2: res_att[b,h,i,j].  Block = (i-tile 16, h, b); 256 thr = (j_l 32, ig 4, dh 2).
// Each thread: 4 i's (ig*4+il), d-half dh. kr staged per 32-j chunk in LDS.
__global__ __launch_bounds__(256,3) void k2_att(
    const float* __restrict__ nt, const float* __restrict__ adj,
    const float* __restrict__ ets, const float* __restrict__ rel_pri,
    const float* __restrict__ q_ws, const float* __restrict__ kr_ws,
    float* __restrict__ res_att)
{
  __shared__ float q_s[16*68];
  __shared__ float kr_s[32*260];
  __shared__ float ntj_s[32*4];
  __shared__ float nti_s[16*4];
  int it = blockIdx.x, h = blockIdx.y, b = blockIdx.z;
  int i0 = it*16;
  int tid = threadIdx.x;
  int j_l = tid>>3, ig = (tid>>1)&3, dh = tid&1;
  // stage q (16 nodes x 64 f), layout [i][t*16+d], row padded to 68
  {
    int i = tid>>4, f = (tid&15)*4;
    float4 qv = *(const float4*)&q_ws[((size_t)(h*Bq*Nn) + b*Nn + i0 + i)*64 + f];
    *(float4*)&q_s[i*68 + f] = qv;
  }
  if (tid < 64) nti_s[tid] = nt[(size_t)(b*Nn + i0 + (tid>>2))*TT + (tid&3)];
  float cr0 = rel_pri[0*HH+h]*0.25f, cr1 = rel_pri[1*HH+h]*0.25f;
  float cr2 = rel_pri[2*HH+h]*0.25f, cr3 = rel_pri[3*HH+h]*0.25f;
  float crr[4] = {cr0, cr1, cr2, cr3};

  for (int jc = 0; jc < 12; ++jc) {
    __syncthreads();
    {
      int js = tid>>3, gb = tid&7;
      const float* src = &kr_ws[((size_t)(h*Bq*Nn) + b*Nn + jc*32 + js)*256];
      float* dst = &kr_s[js*260];
#pragma unroll
      for (int gl = 0; gl < 8; ++gl) {
        int g = gl*8 + gb;                       // src granule: r*16 + s*4 + qd
        float4 v = *(const float4*)&src[g*4];
        int r = g>>4, s = (g>>2)&3, qd = g&3;
        int gd = (qd>>1)*32 + r*8 + s*2 + (qd&1);  // dest: [dh][r][s][e]
        *(float4*)&dst[gd*4] = v;
      }
      if (tid < 128) ntj_s[tid] = nt[(size_t)(b*Nn + jc*32 + (tid>>2))*TT + (tid&3)];
    }
    __syncthreads();
    int j = jc*32 + j_l;
    float nt0 = ntj_s[j_l*4+0], nt1 = ntj_s[j_l*4+1];
    float nt2 = ntj_s[j_l*4+2], nt3 = ntj_s[j_l*4+3];
    float qn[4][8];
#pragma unroll
    for (int il = 0; il < 4; ++il) {
      int ib = (ig*4 + il)*68 + dh*8;
#pragma unroll
      for (int dp = 0; dp < 8; ++dp)
        qn[il][dp] = q_s[ib+dp]*nt0 + q_s[ib+16+dp]*nt1 + q_s[ib+32+dp]*nt2 + q_s[ib+48+dp]*nt3;
    }
    float mar[4][4];
#pragma unroll
    for (int il = 0; il < 4; ++il) {
      int i = i0 + ig*4 + il;
      float a = adj[((size_t)b*Nn + i)*Nn + j];
      float4 e4 = *(const float4*)&ets[(((size_t)b*Nn + i)*Nn + j)*RR];
      mar[il][0]=e4.x*a; mar[il][1]=e4.y*a; mar[il][2]=e4.z*a; mar[il][3]=e4.w*a;
    }
    float acc[4] = {0.f,0.f,0.f,0.f};
    const float* kbp = &kr_s[j_l*260 + dh*128];
#pragma unroll
    for (int r = 0; r < 4; ++r) {
      float mr0 = mar[0][r]*crr[r], mr1 = mar[1][r]*crr[r];
      float mr2 = mar[2][r]*crr[r], mr3 = mar[3][r]*crr[r];
#pragma unroll
      for (int s = 0; s < 4; ++s) {
        float kk[8];
        *(float4*)&kk[0] = *(const float4*)&kbp[r*32 + s*8];
        *(float4*)&kk[4] = *(const float4*)&kbp[r*32 + s*8 + 4];
        float d0=0,d1=0,d2=0,d3=0;
#pragma unroll
        for (int dp = 0; dp < 8; ++dp) {
          d0 += qn[0][dp]*kk[dp]; d1 += qn[1][dp]*kk[dp];
          d2 += qn[2][dp]*kk[dp]; d3 += qn[3][dp]*kk[dp];
        }
        d0 += __shfl_xor(d0,1); d1 += __shfl_xor(d1,1);
        d2 += __shfl_xor(d2,1); d3 += __shfl_xor(d3,1);
        acc[0] += mr0*nti_s[(ig*4+0)*4+s]*d0;
        acc[1] += mr1*nti_s[(ig*4+1)*4+s]*d1;
        acc[2] += mr2*nti_s[(ig*4+2)*4+s]*d2;
        acc[3] += mr3*nti_s[(ig*4+3)*4+s]*d3;
      }
    }
    if (dh == 0) {
#pragma unroll
      for (int il = 0; il < 4; ++il)
        res_att[((size_t)(b*HH + h)*Nn + i0 + ig*4 + il)*Nn + j] = acc[il];
    }
  }
}

// K3: att_inv[b,h,j] = guarded 1/sum_i res_att
__global__ __launch_bounds__(128) void k3_attsum(
    const float* __restrict__ res_att, float* __restrict__ att_inv)
{
  int jc = blockIdx.x, h = blockIdx.y, b = blockIdx.z;
  int j = jc*128 + threadIdx.x;
  const float* p = res_att + (size_t)(b*HH + h)*Nn*Nn + j;
  float s = 0.f;
  for (int i = 0; i < Nn; ++i) s += p[(size_t)i*Nn];
  att_inv[(size_t)(b*HH + h)*Nn + j] = (s > 1e-6f) ? 1.f/s : 0.f;
}

// ---- K4: agg[b,i,h,d]. Same block structure as K2, + vr staged, accumulates over all j.
__global__ __launch_bounds__(256,2) void k4_agg(
    const float* __restrict__ nt, const float* __restrict__ adj,
    const float* __restrict__ ets, const float* __restrict__ rel_pri,
    const float* __restrict__ q_ws, const float* __restrict__ kr_ws,
    const float* __restrict__ vr_ws, const float* __restrict__ res_att,
    const float* __restrict__ att_inv, float* __restrict__ agg_ws)
{
  __shared__ float q_s[16*68];
  __shared__ float kr_s[32*260];
  __shared__ float vr_s[32*260];
  __shared__ float ntj_s[32*4];
  __shared__ float nti_s[16*4];
  int it = blockIdx.x, h = blockIdx.y, b = blockIdx.z;
  int i0 = it*16;
  int tid = threadIdx.x;
  int j_l = tid>>3, ig = (tid>>1)&3, dh = tid&1;
  {
    int i = tid>>4, f = (tid&15)*4;
    float4 qv = *(const float4*)&q_ws[((size_t)(h*Bq*Nn) + b*Nn + i0 + i)*64 + f];
    *(float4*)&q_s[i*68 + f] = qv;
  }
  if (tid < 64) nti_s[tid] = nt[(size_t)(b*Nn + i0 + (tid>>2))*TT + (tid&3)];
  float crr[4];
#pragma unroll
  for (int r = 0; r < 4; ++r) crr[r] = rel_pri[r*HH+h]*0.25f;

  float agg[4][8];
#pragma unroll
  for (int il = 0; il < 4; ++il)
#pragma unroll
    for (int dp = 0; dp < 8; ++dp) agg[il][dp] = 0.f;

  const float* rab = res_att + (size_t)(b*HH + h)*Nn*Nn;
  const float* aib = att_inv + (size_t)(b*HH + h)*Nn;

  for (int jc = 0; jc < 12; ++jc) {
    __syncthreads();
    {
      int js = tid>>3, gb = tid&7;
      const float* srck = &kr_ws[((size_t)(h*Bq*Nn) + b*Nn + jc*32 + js)*256];
      const float* srcv = &vr_ws[((size_t)(h*Bq*Nn) + b*Nn + jc*32 + js)*256];
      float* dstk = &kr_s[js*260];
      float* dstv = &vr_s[js*260];
#pragma unroll
      for (int gl = 0; gl < 8; ++gl) {
        int g = gl*8 + gb;
        float4 v1 = *(const float4*)&srck[g*4];
        float4 v2 = *(const float4*)&srcv[g*4];
        int r = g>>4, s = (g>>2)&3, qd = g&3;
        int gd = (qd>>1)*32 + r*8 + s*2 + (qd&1);
        *(float4*)&dstk[gd*4] = v1;
        *(float4*)&dstv[gd*4] = v2;
      }
      if (tid < 128) ntj_s[tid] = nt[(size_t)(b*Nn + jc*32 + (tid>>2))*TT + (tid&3)];
    }
    __syncthreads();
    int j = jc*32 + j_l;
    float nt0 = ntj_s[j_l*4+0], nt1 = ntj_s[j_l*4+1];
    float nt2 = ntj_s[j_l*4+2], nt3 = ntj_s[j_l*4+3];
    float qn[4][8];
#pragma unroll
    for (int il = 0; il < 4; ++il) {
      int ib = (ig*4 + il)*68 + dh*8;
#pragma unroll
      for (int dp = 0; dp < 8; ++dp)
        qn[il][dp] = q_s[ib+dp]*nt0 + q_s[ib+16+dp]*nt1 + q_s[ib+32+dp]*nt2 + q_s[ib+48+dp]*nt3;
    }
    float invj = aib[j];
    float mar[4][4], wv[4];
#pragma unroll
    for (int il = 0; il < 4; ++il) {
      int i = i0 + ig*4 + il;
      wv[il] = rab[(size_t)i*Nn + j] * invj;
      float a = adj[((size_t)b*Nn + i)*Nn + j];
      float4 e4 = *(const float4*)&ets[(((size_t)b*Nn + i)*Nn + j)*RR];
      mar[il][0]=e4.x*a; mar[il][1]=e4.y*a; mar[il][2]=e4.z*a; mar[il][3]=e4.w*a;
    }
    const float* kbp = &kr_s[j_l*260 + dh*128];
    const float* vbp = &vr_s[j_l*260 + dh*128];
#pragma unroll
    for (int r = 0; r < 4; ++r) {
      float mr0 = mar[0][r]*crr[r]*wv[0], mr1 = mar[1][r]*crr[r]*wv[1];
      float mr2 = mar[2][r]*crr[r]*wv[2], mr3 = mar[3][r]*crr[r]*wv[3];
#pragma unroll
      for (int s = 0; s < 4; ++s) {
        float kk[8], vv[8];
        *(float4*)&kk[0] = *(const float4*)&kbp[r*32 + s*8];
        *(float4*)&kk[4] = *(const float4*)&kbp[r*32 + s*8 + 4];
        *(float4*)&vv[0] = *(const float4*)&vbp[r*32 + s*8];
        *(float4*)&vv[4] = *(const float4*)&vbp[r*32 + s*8 + 4];
        float d0=0,d1=0,d2=0,d3=0;
#pragma unroll
        for (int dp = 0; dp < 8; ++dp) {
          d0 += qn[0][dp]*kk[dp]; d1 += qn[1][dp]*kk[dp];
          d2 += qn[2][dp]*kk[dp]; d3 += qn[3][dp]*kk[dp];
        }
        d0 += __shfl_xor(d0,1); d1 += __shfl_xor(d1,1);
        d2 += __shfl_xor(d2,1); d3 += __shfl_xor(d3,1);
        float c0 = mr0*nti_s[(ig*4+0)*4+s]*d0;
        float c1 = mr1*nti_s[(ig*4+1)*4+s]*d1;
        float c2 = mr2*nti_s[(ig*4+2)*4+s]*d2;
        float c3 = mr3*nti_s[(ig*4+3)*4+s]*d3;
#pragma unroll
        for (int dp = 0; dp < 8; ++dp) {
          agg[0][dp] += c0*vv[dp]; agg[1][dp] += c1*vv[dp];
          agg[2][dp] += c2*vv[dp]; agg[3][dp] += c3*vv[dp];
        }
      }
    }
  }
  // reduce over j_l (32 partials) via LDS (reuse kr_s)
  __syncthreads();
  float* sc = kr_s;   // need 32*256 = 8192 f <= 8320
#pragma unroll
  for (int il = 0; il < 4; ++il) {
    int iloc = ig*4 + il;
#pragma unroll
    for (int dp = 0; dp < 8; dp += 4)
      *(float4*)&sc[j_l*256 + iloc*16 + dh*8 + dp] = *(float4*)&agg[il][dp];
  }
  __syncthreads();
  {
    int iloc = tid>>4, d = tid&15;
    float ssum = 0.f;
#pragma unroll
    for (int jl = 0; jl < 32; ++jl) ssum += sc[jl*256 + iloc*16 + d];
    agg_ws[((size_t)b*Nn + i0 + iloc)*128 + h*16 + d] = ssum;
  }
}

// K5: trans = agg.aw + ab, GELU, skip-gate, LayerNorm, type-mix
__global__ __launch_bounds__(128) void k5_out(
    const float* __restrict__ agg_ws, const float* __restrict__ nf,
    const float* __restrict__ nt, const float* __restrict__ aw,
    const float* __restrict__ ab, const float* __restrict__ norm_w,
    const float* __restrict__ norm_b, const float* __restrict__ skip,
    float* __restrict__ out)
{
  __shared__ float agg_s[128];
  __shared__ float red[4];
  int n = blockIdx.x, b = blockIdx.y;
  int o = threadIdx.x;
  size_t node = (size_t)b*Nn + n;
  agg_s[o] = agg_ws[node*128 + o];
  __syncthreads();
  float nfo = nf[node*128 + o];
  float outacc = 0.f;
  for (int t = 0; t < TT; ++t) {
    float a = ab[t*128 + o];
    for (int dd = 0; dd < 128; ++dd) a += agg_s[dd] * aw[(size_t)(t*128 + dd)*128 + o];
    float g = 0.5f * a * (1.f + erff(a * 0.70710678118654752f));
    float alpha = 1.f / (1.f + expf(-skip[t]));
    float res = g*alpha + nfo*(1.f - alpha);
    float s1 = res, s2 = res*res;
#pragma unroll
    for (int m = 32; m >= 1; m >>= 1) { s1 += __shfl_xor(s1, m); s2 += __shfl_xor(s2, m); }
    int w = o >> 6;
    if ((o & 63) == 0) { red[w*2] = s1; red[w*2 + 1] = s2; }
    __syncthreads();
    float tot1 = red[0] + red[2], tot2 = red[1] + red[3];
    __syncthreads();
    float mean = tot1 * (1.f/128.f);
    float var  = tot2 * (1.f/128.f) - mean*mean;
    float nrm = (res - mean) * rsqrtf(var + 1e-5f) * norm_w[t*128 + o] + norm_b[t*128 + o];
    outacc += nrm * nt[node*TT + t];
  }
  out[node*128 + o] = outacc;
}

extern "C" void kernel_launch(void* const* d_in, const int* in_sizes, int n_in,
                              void* d_out, int out_size, void* d_ws, size_t ws_size,
                              hipStream_t stream) {
  const float* nf      = (const float*)d_in[0];
  const float* nts     = (const float*)d_in[1];
  const float* adj     = (const float*)d_in[2];
  const float* ets     = (const float*)d_in[3];
  const float* kw      = (const float*)d_in[4];
  const float* kb      = (const float*)d_in[5];
  const float* qw      = (const float*)d_in[6];
  const float* qb      = (const float*)d_in[7];
  const float* vw      = (const float*)d_in[8];
  const float* vb      = (const float*)d_in[9];
  const float* aw      = (const float*)d_in[10];
  const float* ab      = (const float*)d_in[11];
  const float* normw   = (const float*)d_in[12];
  const float* normb   = (const float*)d_in[13];
  const float* rel_pri = (const float*)d_in[14];
  const float* rel_att = (const float*)d_in[15];
  const float* rel_msg = (const float*)d_in[16];
  const float* skip    = (const float*)d_in[17];
  (void)in_sizes; (void)n_in; (void)out_size; (void)ws_size;

  float* ws = (float*)d_ws;
  float* q_ws    = ws;                                  // 8*1536*64   = 786432
  float* kr_ws   = q_ws + (size_t)HH*Bq*Nn*64;          // 8*1536*256  = 3145728
  float* vr_ws   = kr_ws + (size_t)HH*Bq*Nn*256;
  float* res_att = vr_ws + (size_t)HH*Bq*Nn*256;        // 4*8*384*384 = 4718592
  float* att_inv = res_att + (size_t)Bq*HH*Nn*Nn;       // 12288
  float* agg_ws  = att_inv + (size_t)Bq*HH*Nn;          // 196608

  hipLaunchKernelGGL(k1_proj, dim3(192), dim3(128), 0, stream,
                     nf, kw, kb, qw, qb, vw, vb, rel_att, rel_msg, q_ws, kr_ws, vr_ws);
  hipLaunchKernelGGL(k2_att, dim3(24, 8, 4), dim3(256), 0, stream,
                     nts, adj, ets, rel_pri, q_ws, kr_ws, res_att);
  hipLaunchKernelGGL(k3_attsum, dim3(3, 8, 4), dim3(128), 0, stream, res_att, att_inv);
  hipLaunchKernelGGL(k4_agg, dim3(24, 8, 4), dim3(256), 0, stream,
                     nts, adj, ets, rel_pri, q_ws, kr_ws, vr_ws, res_att, att_inv, agg_ws);
  hipLaunchKernelGGL(k5_out, dim3(384, 4), dim3(128), 0, stream,
                     agg_ws, nf, nts, aw, ab, normw, normb, skip, (float*)d_out);
}